// Round 1
// baseline (438.186 us; speedup 1.0000x reference)
//
#include <hip/hip_runtime.h>
#include <math.h>

#define NTOK   16384   // 4 * 4096 tokens
#define DK     2048    // d_model
#define NEXP   64
#define MTILE  64      // tokens per block
#define KHALF  1024    // K range per half-block
#define KCHUNK 32      // k's per staged chunk
#define NCHUNK (KHALF / KCHUNK)   // 32

// Async global->LDS, 16B per lane. dst is the wave-uniform base; HW writes
// dst + lane*16. src is per-lane.
__device__ __forceinline__ void gload_lds16(const float* src, float* dst) {
#if __has_builtin(__builtin_amdgcn_global_load_lds)
    __builtin_amdgcn_global_load_lds(
        (const __attribute__((address_space(1))) void*)src,
        (__attribute__((address_space(3))) void*)dst,
        16, 0, 0);
#else
    const int lane = threadIdx.x & 63;
    ((float4*)dst)[lane] = *(const float4*)src;
#endif
}

__global__ __launch_bounds__(512, 2) void topk_router_kernel(
    const float* __restrict__ x,     // [NTOK][DK]
    const float* __restrict__ Wg,    // [NEXP][DK]
    float* __restrict__ out)         // [NTOK*2] indices (as float) ++ [NTOK*2] weights
{
    // LDS: xs[2 halves][2 bufs][64 tok * 32 k] = 32 KiB, ws same = 32 KiB.
    // Logits [64][65] overlays smem[0..4159] after the K-loop (guarded by barrier).
    __shared__ float smem[16384];   // 64 KiB

    const int tid  = threadIdx.x;
    const int half = tid >> 8;          // 0 or 1 -> K range
    const int htid = tid & 255;
    const int hw   = (tid >> 6) & 3;    // wave index within half
    const int lane = tid & 63;
    const int tn   = htid & 15;         // expert group: experts tn*4 .. +3
    const int tm   = htid >> 4;         // token group:  tokens  tm*4 .. +3
    const int tokbase = blockIdx.x * MTILE;
    const int k0   = half * KHALF;

    // staging lane decomposition: lane = lt*8 + lq ; covers 8 tokens x 32 k per instr
    const int lt = lane >> 3;           // token-within-8
    const int lk = (lane & 7) * 4;      // k word offset (16B granule)

    float* xsh = smem + half * 4096;            // this half's x buffers (2 x 2048)
    float* wsh = smem + 8192 + half * 4096;     // this half's w buffers

    float acc[4][4] = {{0.f,0.f,0.f,0.f},{0.f,0.f,0.f,0.f},
                       {0.f,0.f,0.f,0.f},{0.f,0.f,0.f,0.f}};

    // ---- prologue: stage chunk 0 into buf 0 ----
    {
        const int kc = k0;
        #pragma unroll
        for (int it = 0; it < 2; ++it) {
            const int t8 = hw * 16 + it * 8;
            gload_lds16(&x [(size_t)(tokbase + t8 + lt) * DK + kc + lk], xsh + t8 * 32);
            gload_lds16(&Wg[(size_t)(t8 + lt) * DK + kc + lk],           wsh + t8 * 32);
        }
    }
    __syncthreads();

    int buf = 0;
    #pragma unroll 1
    for (int c = 0; c < NCHUNK; ++c) {
        // prefetch next chunk into the other buffer (loads in flight during compute)
        if (c + 1 < NCHUNK) {
            const int kc = k0 + (c + 1) * KCHUNK;
            float* xb = xsh + (buf ^ 1) * 2048;
            float* wb = wsh + (buf ^ 1) * 2048;
            #pragma unroll
            for (int it = 0; it < 2; ++it) {
                const int t8 = hw * 16 + it * 8;
                gload_lds16(&x [(size_t)(tokbase + t8 + lt) * DK + kc + lk], xb + t8 * 32);
                gload_lds16(&Wg[(size_t)(t8 + lt) * DK + kc + lk],           wb + t8 * 32);
            }
        }

        // compute on current buffer
        {
            const float* xb = xsh + buf * 2048;
            const float* wb = wsh + buf * 2048;
            #pragma unroll
            for (int kg = 0; kg < 8; ++kg) {
                float4 a[4], b[4];
                #pragma unroll
                for (int i = 0; i < 4; ++i)
                    a[i] = *(const float4*)&xb[(tm * 4 + i) * 32 + kg * 4];
                #pragma unroll
                for (int j = 0; j < 4; ++j)
                    b[j] = *(const float4*)&wb[(tn * 4 + j) * 32 + kg * 4];
                #pragma unroll
                for (int i = 0; i < 4; ++i)
                    #pragma unroll
                    for (int j = 0; j < 4; ++j) {
                        acc[i][j] += a[i].x * b[j].x;
                        acc[i][j] += a[i].y * b[j].y;
                        acc[i][j] += a[i].z * b[j].z;
                        acc[i][j] += a[i].w * b[j].w;
                    }
            }
        }
        __syncthreads();   // drains this wave's global_load_lds (vmcnt) + LDS reuse fence
        buf ^= 1;
    }

    // ---- combine K-halves into logits LDS (overlay; safe after barrier) ----
    float* lg = smem;   // [64][65]
    if (half == 0) {
        #pragma unroll
        for (int i = 0; i < 4; ++i)
            #pragma unroll
            for (int j = 0; j < 4; ++j)
                lg[(tm * 4 + i) * 65 + tn * 4 + j] = acc[i][j];
    }
    __syncthreads();
    if (half == 1) {
        #pragma unroll
        for (int i = 0; i < 4; ++i)
            #pragma unroll
            for (int j = 0; j < 4; ++j)
                lg[(tm * 4 + i) * 65 + tn * 4 + j] += acc[i][j];
    }
    __syncthreads();

    // ---- top-2 per token: one wave per token, lane = expert ----
    const int wv = tid >> 6;            // 0..7, each wave handles 8 tokens
    #pragma unroll 1
    for (int t = 0; t < 8; ++t) {
        const int tok = wv * 8 + t;
        const float v = lg[tok * 65 + lane];

        // argmax (tie -> lower index, matching lax.top_k)
        float m1 = v; int i1 = lane;
        #pragma unroll
        for (int off = 32; off > 0; off >>= 1) {
            float ov = __shfl_xor(m1, off);
            int   oi = __shfl_xor(i1, off);
            if (ov > m1 || (ov == m1 && oi < i1)) { m1 = ov; i1 = oi; }
        }
        // second max: mask out winner
        float m2 = (lane == i1) ? -INFINITY : v; int i2 = lane;
        #pragma unroll
        for (int off = 32; off > 0; off >>= 1) {
            float ov = __shfl_xor(m2, off);
            int   oi = __shfl_xor(i2, off);
            if (ov > m2 || (ov == m2 && oi < i2)) { m2 = ov; i2 = oi; }
        }

        if (lane == 0) {
            const int gtok = tokbase + tok;
            // softmax denominator cancels: w1 = p1/(p1+p2) = 1/(1+e^{l2-l1})
            const float e  = expf(m2 - m1);
            const float w1 = 1.0f / (1.0f + e);
            const float w2 = e / (1.0f + e);
            out[gtok * 2 + 0] = (float)i1;
            out[gtok * 2 + 1] = (float)i2;
            out[NTOK * 2 + gtok * 2 + 0] = w1;
            out[NTOK * 2 + gtok * 2 + 1] = w2;
        }
    }
}

extern "C" void kernel_launch(void* const* d_in, const int* in_sizes, int n_in,
                              void* d_out, int out_size, void* d_ws, size_t ws_size,
                              hipStream_t stream) {
    const float* x  = (const float*)d_in[0];
    const float* Wg = (const float*)d_in[1];
    float* out = (float*)d_out;
    hipLaunchKernelGGL(topk_router_kernel, dim3(NTOK / MTILE), dim3(512), 0, stream,
                       x, Wg, out);
}

// Round 2
// 99.650 us; speedup vs baseline: 4.3973x; 4.3973x over previous
//
#include <hip/hip_runtime.h>
#include <math.h>

#define NTOK   16384   // 4 * 4096 tokens
#define DK     2048    // d_model
#define NEXP   64
#define MTILE  64      // tokens per block
#define KHALF  1024    // K range per half-block
#define KCHUNK 32      // k's per staged chunk
#define NCHUNK (KHALF / KCHUNK)   // 32

// Async global->LDS, 16B per lane. dst is the wave-uniform base; HW writes
// dst + lane*16. src is per-lane.
__device__ __forceinline__ void gload_lds16(const float* src, float* dst) {
#if __has_builtin(__builtin_amdgcn_global_load_lds)
    __builtin_amdgcn_global_load_lds(
        (const __attribute__((address_space(1))) void*)src,
        (__attribute__((address_space(3))) void*)dst,
        16, 0, 0);
#else
    const int lane = threadIdx.x & 63;
    ((float4*)dst)[lane] = *(const float4*)src;
#endif
}

// XOR bank swizzle: word-offset within a 32-float row is XORed with
// ((row>>2)&7)<<2. Read-side distinct rows are {4*tn+j} / {4*tm+i}, so
// row>>2 = tn / tm spreads 16 b-rows over 8 bank groups (2-way = free)
// and 4 a-rows over 4 groups (conflict-free). Involution: applied to the
// global SOURCE address at staging (dest stays linear for global_load_lds)
// and again on the LDS read address.
__device__ __forceinline__ int swz(int row) { return ((row >> 2) & 7) << 2; }

__global__ __launch_bounds__(512, 2) void topk_router_kernel(
    const float* __restrict__ x,     // [NTOK][DK]
    const float* __restrict__ Wg,    // [NEXP][DK]
    float* __restrict__ out)         // [NTOK*2] indices (as float) ++ [NTOK*2] weights
{
    // LDS: xs[2 halves][2 bufs][64 tok * 32 k] = 32 KiB, ws same = 32 KiB.
    // Logits [64][65] overlays smem[0..4159] after the K-loop (guarded by barrier).
    __shared__ float smem[16384];   // 64 KiB

    const int tid  = threadIdx.x;
    const int half = tid >> 8;          // 0 or 1 -> K range
    const int htid = tid & 255;
    const int hw   = (tid >> 6) & 3;    // wave index within half
    const int lane = tid & 63;
    const int tn   = htid & 15;         // expert group: experts tn*4 .. +3
    const int tm   = htid >> 4;         // token group:  tokens  tm*4 .. +3
    const int tokbase = blockIdx.x * MTILE;
    const int k0   = half * KHALF;

    // staging lane decomposition: lane = lt*8 + lq ; covers 8 tokens x 32 k per instr
    const int lt = lane >> 3;           // token-within-8
    const int lk = (lane & 7) * 4;      // k word offset (16B granule)

    float* xsh = smem + half * 4096;            // this half's x buffers (2 x 2048)
    float* wsh = smem + 8192 + half * 4096;     // this half's w buffers

    float acc[4][4] = {{0.f,0.f,0.f,0.f},{0.f,0.f,0.f,0.f},
                       {0.f,0.f,0.f,0.f},{0.f,0.f,0.f,0.f}};

    // ---- prologue: stage chunk 0 into buf 0 (source pre-swizzled) ----
    {
        const int kc = k0;
        #pragma unroll
        for (int it = 0; it < 2; ++it) {
            const int t8  = hw * 16 + it * 8;
            const int row = t8 + lt;
            const int wo  = kc + (lk ^ swz(row));
            gload_lds16(&x [(size_t)(tokbase + row) * DK + wo], xsh + t8 * 32);
            gload_lds16(&Wg[(size_t)(row) * DK + wo],           wsh + t8 * 32);
        }
    }
    __syncthreads();

    int buf = 0;
    #pragma unroll 1
    for (int c = 0; c < NCHUNK; ++c) {
        // prefetch next chunk into the other buffer (loads in flight during compute)
        if (c + 1 < NCHUNK) {
            const int kc = k0 + (c + 1) * KCHUNK;
            float* xb = xsh + (buf ^ 1) * 2048;
            float* wb = wsh + (buf ^ 1) * 2048;
            #pragma unroll
            for (int it = 0; it < 2; ++it) {
                const int t8  = hw * 16 + it * 8;
                const int row = t8 + lt;
                const int wo  = kc + (lk ^ swz(row));
                gload_lds16(&x [(size_t)(tokbase + row) * DK + wo], xb + t8 * 32);
                gload_lds16(&Wg[(size_t)(row) * DK + wo],           wb + t8 * 32);
            }
        }

        // compute on current buffer (reads use the same XOR swizzle)
        {
            const float* xb = xsh + buf * 2048;
            const float* wb = wsh + buf * 2048;
            const int swa = swz(tm * 4);    // row>>2 == tm for all i in 0..3
            const int swb = swz(tn * 4);    // row>>2 == tn for all j in 0..3
            #pragma unroll
            for (int kg = 0; kg < 8; ++kg) {
                float4 a[4], b[4];
                #pragma unroll
                for (int i = 0; i < 4; ++i)
                    a[i] = *(const float4*)&xb[(tm * 4 + i) * 32 + ((kg * 4) ^ swa)];
                #pragma unroll
                for (int j = 0; j < 4; ++j)
                    b[j] = *(const float4*)&wb[(tn * 4 + j) * 32 + ((kg * 4) ^ swb)];
                #pragma unroll
                for (int i = 0; i < 4; ++i)
                    #pragma unroll
                    for (int j = 0; j < 4; ++j) {
                        acc[i][j] += a[i].x * b[j].x;
                        acc[i][j] += a[i].y * b[j].y;
                        acc[i][j] += a[i].z * b[j].z;
                        acc[i][j] += a[i].w * b[j].w;
                    }
            }
        }
        __syncthreads();   // drains this wave's global_load_lds (vmcnt) + LDS reuse fence
        buf ^= 1;
    }

    // ---- combine K-halves into logits LDS (overlay; safe after barrier) ----
    float* lg = smem;   // [64][65]
    if (half == 0) {
        #pragma unroll
        for (int i = 0; i < 4; ++i)
            #pragma unroll
            for (int j = 0; j < 4; ++j)
                lg[(tm * 4 + i) * 65 + tn * 4 + j] = acc[i][j];
    }
    __syncthreads();
    if (half == 1) {
        #pragma unroll
        for (int i = 0; i < 4; ++i)
            #pragma unroll
            for (int j = 0; j < 4; ++j)
                lg[(tm * 4 + i) * 65 + tn * 4 + j] += acc[i][j];
    }
    __syncthreads();

    // ---- top-2 per token: one wave per token, lane = expert ----
    const int wv = tid >> 6;            // 0..7, each wave handles 8 tokens
    #pragma unroll 1
    for (int t = 0; t < 8; ++t) {
        const int tok = wv * 8 + t;
        const float v = lg[tok * 65 + lane];

        // argmax (tie -> lower index, matching lax.top_k)
        float m1 = v; int i1 = lane;
        #pragma unroll
        for (int off = 32; off > 0; off >>= 1) {
            float ov = __shfl_xor(m1, off);
            int   oi = __shfl_xor(i1, off);
            if (ov > m1 || (ov == m1 && oi < i1)) { m1 = ov; i1 = oi; }
        }
        // second max: mask out winner
        float m2 = (lane == i1) ? -INFINITY : v; int i2 = lane;
        #pragma unroll
        for (int off = 32; off > 0; off >>= 1) {
            float ov = __shfl_xor(m2, off);
            int   oi = __shfl_xor(i2, off);
            if (ov > m2 || (ov == m2 && oi < i2)) { m2 = ov; i2 = oi; }
        }

        if (lane == 0) {
            const int gtok = tokbase + tok;
            // softmax denominator cancels: w1 = p1/(p1+p2) = 1/(1+e^{l2-l1})
            const float e  = expf(m2 - m1);
            const float w1 = 1.0f / (1.0f + e);
            const float w2 = e / (1.0f + e);
            out[gtok * 2 + 0] = (float)i1;
            out[gtok * 2 + 1] = (float)i2;
            out[NTOK * 2 + gtok * 2 + 0] = w1;
            out[NTOK * 2 + gtok * 2 + 1] = w2;
        }
    }
}

extern "C" void kernel_launch(void* const* d_in, const int* in_sizes, int n_in,
                              void* d_out, int out_size, void* d_ws, size_t ws_size,
                              hipStream_t stream) {
    const float* x  = (const float*)d_in[0];
    const float* Wg = (const float*)d_in[1];
    float* out = (float*)d_out;
    hipLaunchKernelGGL(topk_router_kernel, dim3(NTOK / MTILE), dim3(512), 0, stream,
                       x, Wg, out);
}